// Round 1
// baseline (1825.410 us; speedup 1.0000x reference)
//
#include <hip/hip_runtime.h>

// MQA: B=2, S=2048, HID=2048, NH=16, HD=128
#define B_   2
#define S_   2048
#define HID_ 2048
#define NH_  16
#define HD_  128
#define M_   (B_ * S_)   // 4096 total rows

using half8   = __attribute__((ext_vector_type(8))) _Float16;
using floatx4 = __attribute__((ext_vector_type(4))) float;

// ---------------------------------------------------------------------------
// fp32 -> fp16 conversion, 8 elems / thread
// ---------------------------------------------------------------------------
__global__ __launch_bounds__(256) void cvt_f16_kernel(
    const float* __restrict__ src, _Float16* __restrict__ dst, int n8) {
  int i = blockIdx.x * 256 + threadIdx.x;
  if (i >= n8) return;
  const floatx4* s = (const floatx4*)src;
  floatx4 a = s[(size_t)i * 2];
  floatx4 b = s[(size_t)i * 2 + 1];
  half8 h;
  h[0] = (_Float16)a[0]; h[1] = (_Float16)a[1];
  h[2] = (_Float16)a[2]; h[3] = (_Float16)a[3];
  h[4] = (_Float16)b[0]; h[5] = (_Float16)b[1];
  h[6] = (_Float16)b[2]; h[7] = (_Float16)b[3];
  *(half8*)(dst + (size_t)i * 8) = h;
}

// ---------------------------------------------------------------------------
// C[M,N] = A[M,K] @ W[N,K]^T + bias   (fp16 inputs, fp32 accum/output)
// 128x128 block tile, BK=32, 4 waves in 2x2, each wave 64x64 via 4x4 MFMAs.
// mfma_f32_16x16x32_f16: A/B frag = 8 fp16 (lane: idx=lane&15, k=(lane>>4)*8+j)
// C/D frag: col=lane&15, row=(lane>>4)*4+reg   [verified layout, guide §3]
// ---------------------------------------------------------------------------
__global__ __launch_bounds__(256) void gemm_bt_f16(
    const _Float16* __restrict__ A, const _Float16* __restrict__ W,
    const float* __restrict__ bias, float* __restrict__ C, int N, int K) {
  constexpr int BK = 32, BKP = 40;  // pitch 40 halfs = 80B (16B aligned, conflict-light)
  __shared__ __align__(16) _Float16 As[128][BKP];
  __shared__ __align__(16) _Float16 Ws[128][BKP];

  const int tid  = threadIdx.x;
  const int lane = tid & 63;
  const int wave = tid >> 6;
  const int wm   = wave >> 1, wn = wave & 1;
  const int m0   = blockIdx.y * 128, n0 = blockIdx.x * 128;
  const int lrow = lane & 15;
  const int kq   = (lane >> 4) * 8;
  const int r0   = tid >> 2;            // 0..63
  const int cc0  = (tid & 3) * 8;       // 0,8,16,24

  floatx4 acc[4][4];
#pragma unroll
  for (int i = 0; i < 4; i++)
#pragma unroll
    for (int j = 0; j < 4; j++) acc[i][j] = (floatx4){0.f, 0.f, 0.f, 0.f};

  const _Float16* Ap0 = A + (size_t)(m0 + r0) * K + cc0;
  const _Float16* Ap1 = A + (size_t)(m0 + r0 + 64) * K + cc0;
  const _Float16* Wp0 = W + (size_t)(n0 + r0) * K + cc0;
  const _Float16* Wp1 = W + (size_t)(n0 + r0 + 64) * K + cc0;

  for (int kt = 0; kt < K; kt += BK) {
    *(half8*)&As[r0][cc0]      = *(const half8*)(Ap0 + kt);
    *(half8*)&As[r0 + 64][cc0] = *(const half8*)(Ap1 + kt);
    *(half8*)&Ws[r0][cc0]      = *(const half8*)(Wp0 + kt);
    *(half8*)&Ws[r0 + 64][cc0] = *(const half8*)(Wp1 + kt);
    __syncthreads();

    half8 af[4], bf[4];
#pragma unroll
    for (int i = 0; i < 4; i++)
      af[i] = *(const half8*)&As[wm * 64 + i * 16 + lrow][kq];
#pragma unroll
    for (int j = 0; j < 4; j++)
      bf[j] = *(const half8*)&Ws[wn * 64 + j * 16 + lrow][kq];
#pragma unroll
    for (int i = 0; i < 4; i++)
#pragma unroll
      for (int j = 0; j < 4; j++)
        acc[i][j] = __builtin_amdgcn_mfma_f32_16x16x32_f16(af[i], bf[j], acc[i][j], 0, 0, 0);
    __syncthreads();
  }

  const int rq = (lane >> 4) * 4;
#pragma unroll
  for (int j = 0; j < 4; j++) {
    int col  = n0 + wn * 64 + j * 16 + lrow;
    float bv = bias[col];
#pragma unroll
    for (int i = 0; i < 4; i++) {
      int row = m0 + wm * 64 + i * 16 + rq;
#pragma unroll
      for (int r = 0; r < 4; r++)
        C[(size_t)(row + r) * N + col] = acc[i][j][r] + bv;
    }
  }
}

// ---------------------------------------------------------------------------
// Flash attention (fp32 vector math). One block = 64 q-rows of one (b,h).
// Q/K transposed in LDS ([d][m], pitch 68 -> 16B aligned float4, few conflicts)
// scores 4x4/thread -> Ps -> per-row online softmax -> PV 4x8/thread.
// Writes attn output as fp16 at (b*S+s)*HID + h*HD + d for the O-projection.
// ---------------------------------------------------------------------------
__global__ __launch_bounds__(256) void attn_kernel(
    const float* __restrict__ Q, const float* __restrict__ K,
    const float* __restrict__ V, const int* __restrict__ mask,
    _Float16* __restrict__ Obuf) {
  constexpr int BM = 64, BN = 64;
  __shared__ __align__(16) float Qs[HD_][BM + 4];
  __shared__ __align__(16) float Ks[HD_][BN + 4];
  __shared__ __align__(16) float Vs[BN][HD_];
  __shared__ float Ps[BM][BN + 1];
  __shared__ float row_m[BM], row_l[BM], row_al[BM];
  __shared__ int   mk[BN];

  const int tid = threadIdx.x;
  const int tx  = tid & 15, ty = tid >> 4;
  const int q0  = blockIdx.x * BM;
  const int bh  = blockIdx.y;
  const int b   = bh >> 4, h = bh & 15;
  const float scale = 0.08838834764831845f;  // 1/sqrt(128)

  // load Q tile, transposed into LDS
#pragma unroll
  for (int it = 0; it < 8; it++) {
    int i = it * 256 + tid;       // 2048 float4 chunks
    int m = i >> 5;               // 32 chunks per 128-dim row
    int d = (i & 31) * 4;
    floatx4 v = *(const floatx4*)(Q + (size_t)(b * S_ + q0 + m) * HID_ + h * HD_ + d);
    Qs[d][m] = v[0]; Qs[d + 1][m] = v[1]; Qs[d + 2][m] = v[2]; Qs[d + 3][m] = v[3];
  }
  if (tid < BM) { row_m[tid] = -1e30f; row_l[tid] = 0.f; }

  float acc_o[4][8];
#pragma unroll
  for (int i = 0; i < 4; i++)
#pragma unroll
    for (int dd = 0; dd < 8; dd++) acc_o[i][dd] = 0.f;

  for (int n0 = 0; n0 < S_; n0 += BN) {
    __syncthreads();  // previous tile's PV done before overwriting Ks/Vs/Ps
#pragma unroll
    for (int it = 0; it < 8; it++) {
      int i = it * 256 + tid;
      int n = i >> 5;
      int d = (i & 31) * 4;
      floatx4 kv = *(const floatx4*)(K + (size_t)(b * S_ + n0 + n) * HD_ + d);
      Ks[d][n] = kv[0]; Ks[d + 1][n] = kv[1]; Ks[d + 2][n] = kv[2]; Ks[d + 3][n] = kv[3];
      floatx4 vv = *(const floatx4*)(V + (size_t)(b * S_ + n0 + n) * HD_ + d);
      *(floatx4*)&Vs[n][d] = vv;
    }
    if (tid < BN) mk[tid] = mask[b * S_ + n0 + tid];
    __syncthreads();

    // scores: 4x4 per thread
    float sc[4][4];
#pragma unroll
    for (int i = 0; i < 4; i++)
#pragma unroll
      for (int j = 0; j < 4; j++) sc[i][j] = 0.f;
#pragma unroll 4
    for (int d = 0; d < HD_; d++) {
      floatx4 qa = *(const floatx4*)&Qs[d][ty * 4];
      floatx4 kb = *(const floatx4*)&Ks[d][tx * 4];
#pragma unroll
      for (int i = 0; i < 4; i++)
#pragma unroll
        for (int j = 0; j < 4; j++) sc[i][j] += qa[i] * kb[j];
    }
#pragma unroll
    for (int i = 0; i < 4; i++)
#pragma unroll
      for (int j = 0; j < 4; j++) {
        float s = sc[i][j] * scale;
        if (mk[tx * 4 + j] == 0) s = -1e30f;
        Ps[ty * 4 + i][tx * 4 + j] = s;
      }
    __syncthreads();

    // per-row online softmax stats (64 rows on first 64 threads)
    if (tid < BM) {
      int r = tid;
      float mold = row_m[r];
      float tm = -1e30f;
      for (int n = 0; n < BN; n++) tm = fmaxf(tm, Ps[r][n]);
      float mnew = fmaxf(mold, tm);
      float al   = __expf(mold - mnew);
      float sum  = 0.f;
      for (int n = 0; n < BN; n++) {
        float pv = __expf(Ps[r][n] - mnew);
        Ps[r][n] = pv;
        sum += pv;
      }
      row_m[r]  = mnew;
      row_l[r]  = row_l[r] * al + sum;
      row_al[r] = al;
    }
    __syncthreads();

    // PV: rows ty*4.., dims tx*8..
    float al[4];
#pragma unroll
    for (int i = 0; i < 4; i++) al[i] = row_al[ty * 4 + i];
#pragma unroll
    for (int i = 0; i < 4; i++)
#pragma unroll
      for (int dd = 0; dd < 8; dd++) acc_o[i][dd] *= al[i];
    for (int n = 0; n < BN; n++) {
      floatx4 v0 = *(const floatx4*)&Vs[n][tx * 8];
      floatx4 v1 = *(const floatx4*)&Vs[n][tx * 8 + 4];
      float p[4];
#pragma unroll
      for (int i = 0; i < 4; i++) p[i] = Ps[ty * 4 + i][n];
#pragma unroll
      for (int i = 0; i < 4; i++) {
#pragma unroll
        for (int dd = 0; dd < 4; dd++) acc_o[i][dd] += p[i] * v0[dd];
#pragma unroll
        for (int dd = 0; dd < 4; dd++) acc_o[i][dd + 4] += p[i] * v1[dd];
      }
    }
  }
  __syncthreads();

#pragma unroll
  for (int i = 0; i < 4; i++) {
    float inv = 1.0f / row_l[ty * 4 + i];
    half8 o;
#pragma unroll
    for (int dd = 0; dd < 8; dd++) o[dd] = (_Float16)(acc_o[i][dd] * inv);
    *(half8*)(Obuf + (size_t)(b * S_ + q0 + ty * 4 + i) * HID_ + h * HD_ + tx * 8) = o;
  }
}

// ---------------------------------------------------------------------------
extern "C" void kernel_launch(void* const* d_in, const int* in_sizes, int n_in,
                              void* d_out, int out_size, void* d_ws, size_t ws_size,
                              hipStream_t stream) {
  const float* hidden = (const float*)d_in[0];
  const int*   mask   = (const int*)d_in[1];
  const float* Wq = (const float*)d_in[2];
  const float* bq = (const float*)d_in[3];
  const float* Wk = (const float*)d_in[4];
  const float* bk = (const float*)d_in[5];
  const float* Wv = (const float*)d_in[6];
  const float* bv = (const float*)d_in[7];
  const float* Wo = (const float*)d_in[8];
  const float* bo = (const float*)d_in[9];
  float* out = (float*)d_out;

  // workspace carve-up (~85 MB total)
  char* p = (char*)d_ws;
  auto alloc = [&](size_t bytes) {
    char* r = p;
    p += (bytes + 255) & ~(size_t)255;
    return r;
  };
  _Float16* hidh  = (_Float16*)alloc((size_t)M_ * HID_ * 2);
  _Float16* Wqh   = (_Float16*)alloc((size_t)HID_ * HID_ * 2);
  _Float16* Wkh   = (_Float16*)alloc((size_t)HD_ * HID_ * 2);
  _Float16* Wvh   = (_Float16*)alloc((size_t)HD_ * HID_ * 2);
  _Float16* Woh   = (_Float16*)alloc((size_t)HID_ * HID_ * 2);
  float*    Qb    = (float*)alloc((size_t)M_ * HID_ * 4);
  float*    Kb    = (float*)alloc((size_t)M_ * HD_ * 4);
  float*    Vb    = (float*)alloc((size_t)M_ * HD_ * 4);
  _Float16* attnh = (_Float16*)alloc((size_t)M_ * HID_ * 2);

  // fp32 -> fp16 casts
  {
    int n8;
    n8 = M_ * HID_ / 8;
    cvt_f16_kernel<<<(n8 + 255) / 256, 256, 0, stream>>>(hidden, hidh, n8);
    n8 = HID_ * HID_ / 8;
    cvt_f16_kernel<<<(n8 + 255) / 256, 256, 0, stream>>>(Wq, Wqh, n8);
    n8 = HD_ * HID_ / 8;
    cvt_f16_kernel<<<(n8 + 255) / 256, 256, 0, stream>>>(Wk, Wkh, n8);
    cvt_f16_kernel<<<(n8 + 255) / 256, 256, 0, stream>>>(Wv, Wvh, n8);
    n8 = HID_ * HID_ / 8;
    cvt_f16_kernel<<<(n8 + 255) / 256, 256, 0, stream>>>(Wo, Woh, n8);
  }

  // projections
  dim3 gq(HID_ / 128, M_ / 128);  // (16, 32)
  dim3 gk(HD_ / 128, M_ / 128);   // (1, 32)
  gemm_bt_f16<<<gq, 256, 0, stream>>>(hidh, Wqh, bq, Qb, HID_, HID_);
  gemm_bt_f16<<<gk, 256, 0, stream>>>(hidh, Wkh, bk, Kb, HD_, HID_);
  gemm_bt_f16<<<gk, 256, 0, stream>>>(hidh, Wvh, bv, Vb, HD_, HID_);

  // attention
  dim3 ga(S_ / 64, B_ * NH_);  // (32, 32)
  attn_kernel<<<ga, 256, 0, stream>>>(Qb, Kb, Vb, mask, attnh);

  // output projection -> d_out
  gemm_bt_f16<<<gq, 256, 0, stream>>>(attnh, Woh, bo, out, HID_, HID_);
}

// Round 4
// 443.651 us; speedup vs baseline: 4.1145x; 4.1145x over previous
//
#include <hip/hip_runtime.h>

// MQA: B=2, S=2048, HID=2048, NH=16, HD=128
#define B_   2
#define S_   2048
#define HID_ 2048
#define NH_  16
#define HD_  128
#define M_   (B_ * S_)   // 4096 total rows

using half8   = __attribute__((ext_vector_type(8))) _Float16;
using floatx4 = __attribute__((ext_vector_type(4))) float;

// ---------------------------------------------------------------------------
// fp32 -> fp16 conversion, 8 elems / thread
// ---------------------------------------------------------------------------
__global__ __launch_bounds__(256) void cvt_f16_kernel(
    const float* __restrict__ src, _Float16* __restrict__ dst, int n8) {
  int i = blockIdx.x * 256 + threadIdx.x;
  if (i >= n8) return;
  const floatx4* s = (const floatx4*)src;
  floatx4 a = s[(size_t)i * 2];
  floatx4 b = s[(size_t)i * 2 + 1];
  half8 h;
  h[0] = (_Float16)a[0]; h[1] = (_Float16)a[1];
  h[2] = (_Float16)a[2]; h[3] = (_Float16)a[3];
  h[4] = (_Float16)b[0]; h[5] = (_Float16)b[1];
  h[6] = (_Float16)b[2]; h[7] = (_Float16)b[3];
  *(half8*)(dst + (size_t)i * 8) = h;
}

// ---------------------------------------------------------------------------
// C[M,N] = A[M,K] @ W[N,K]^T + bias  (fp16 in, fp32 accum, OutT out)
// Block tile BM x 128, BK=32. 4 waves in 2x2; wave tile (BM/2) x 64.
// ---------------------------------------------------------------------------
template <int BM, typename OutT>
__device__ __forceinline__ void gemm_body(
    const _Float16* __restrict__ A, const _Float16* __restrict__ W,
    const float* __restrict__ bias, OutT* __restrict__ C,
    int N, int K, int m0, int n0) {
  constexpr int BKP = 40;           // pitch 40 halfs = 80B
  constexpr int MI  = BM / 32;      // frags per wave in m
  __shared__ __align__(16) _Float16 As[BM][BKP];
  __shared__ __align__(16) _Float16 Ws[128][BKP];

  const int tid  = threadIdx.x;
  const int lane = tid & 63;
  const int wave = tid >> 6;
  const int wm   = wave >> 1, wn = wave & 1;
  const int l15  = lane & 15;
  const int kq   = (lane >> 4) * 8;
  const int r0   = tid >> 2;            // 0..63
  const int cc0  = (tid & 3) * 8;       // 0,8,16,24

  floatx4 acc[MI][4];
#pragma unroll
  for (int i = 0; i < MI; i++)
#pragma unroll
    for (int j = 0; j < 4; j++) acc[i][j] = (floatx4){0.f, 0.f, 0.f, 0.f};

  const _Float16* Ap0 = A + (size_t)(m0 + r0) * K + cc0;
  const _Float16* Wp0 = W + (size_t)(n0 + r0) * K + cc0;
  const _Float16* Wp1 = W + (size_t)(n0 + r0 + 64) * K + cc0;

  for (int kt = 0; kt < K; kt += 32) {
    *(half8*)&As[r0][cc0] = *(const half8*)(Ap0 + kt);
    if (BM == 128)
      *(half8*)&As[r0 + 64][cc0] = *(const half8*)(A + (size_t)(m0 + r0 + 64) * K + cc0 + kt);
    *(half8*)&Ws[r0][cc0]      = *(const half8*)(Wp0 + kt);
    *(half8*)&Ws[r0 + 64][cc0] = *(const half8*)(Wp1 + kt);
    __syncthreads();

    half8 af[MI], bf[4];
#pragma unroll
    for (int i = 0; i < MI; i++)
      af[i] = *(const half8*)&As[wm * (BM / 2) + i * 16 + l15][kq];
#pragma unroll
    for (int j = 0; j < 4; j++)
      bf[j] = *(const half8*)&Ws[wn * 64 + j * 16 + l15][kq];
#pragma unroll
    for (int i = 0; i < MI; i++)
#pragma unroll
      for (int j = 0; j < 4; j++)
        acc[i][j] = __builtin_amdgcn_mfma_f32_16x16x32_f16(af[i], bf[j], acc[i][j], 0, 0, 0);
    __syncthreads();
  }

  const int rq = (lane >> 4) * 4;
#pragma unroll
  for (int j = 0; j < 4; j++) {
    int col  = n0 + wn * 64 + j * 16 + l15;
    float bv = bias[col];
#pragma unroll
    for (int i = 0; i < MI; i++) {
      int row = m0 + wm * (BM / 2) + i * 16 + rq;
#pragma unroll
      for (int r = 0; r < 4; r++)
        C[(size_t)(row + r) * N + col] = (OutT)(acc[i][j][r] + bv);
    }
  }
}

__global__ __launch_bounds__(256) void gemm_q(
    const _Float16* __restrict__ A, const _Float16* __restrict__ W,
    const float* __restrict__ bias, _Float16* __restrict__ C, int N, int K) {
  gemm_body<128, _Float16>(A, W, bias, C, N, K, blockIdx.y * 128, blockIdx.x * 128);
}

__global__ __launch_bounds__(256) void gemm_o(
    const _Float16* __restrict__ A, const _Float16* __restrict__ W,
    const float* __restrict__ bias, float* __restrict__ C, int N, int K) {
  gemm_body<128, float>(A, W, bias, C, N, K, blockIdx.y * 128, blockIdx.x * 128);
}

// K and V projections fused: grid.x in {0,1} selects which; BM=64 -> 128 blocks
__global__ __launch_bounds__(256) void gemm_kv(
    const _Float16* __restrict__ A,
    const _Float16* __restrict__ Wk, const float* __restrict__ bk, _Float16* __restrict__ Kh,
    const _Float16* __restrict__ Wv, const float* __restrict__ bv, _Float16* __restrict__ Vh) {
  if (blockIdx.x == 0)
    gemm_body<64, _Float16>(A, Wk, bk, Kh, HD_, HID_, blockIdx.y * 64, 0);
  else
    gemm_body<64, _Float16>(A, Wv, bv, Vh, HD_, HID_, blockIdx.y * 64, 0);
}

// ---------------------------------------------------------------------------
// MFMA flash attention. Block = 128 q-rows of one (b,h); 4 waves x 32 rows.
// Q frags in registers; K row-major LDS; V transposed LDS (kv-major staging
// so the column writes are conflict-free); P -> LDS (fp16) for the C->A
// layout transform; online softmax in registers with 16-lane butterflies.
// ---------------------------------------------------------------------------
__global__ __launch_bounds__(256, 2) void attn_mfma(
    const _Float16* __restrict__ Q, const _Float16* __restrict__ K,
    const _Float16* __restrict__ V, const int* __restrict__ mask,
    _Float16* __restrict__ Obuf) {
  constexpr int BM = 128, BN = 64, KP = 136, VP = 72, PP = 72;
  __shared__ __align__(16) _Float16 Ks[BN][KP];
  __shared__ __align__(16) _Float16 Vt[HD_][VP];
  __shared__ __align__(16) _Float16 Ps[BM][PP];
  __shared__ int mk[BN];

  const int tid  = threadIdx.x;
  const int lane = tid & 63, wave = tid >> 6;
  const int l15  = lane & 15, lq = lane >> 4;
  const int q0   = blockIdx.x * BM;
  const int b    = blockIdx.y >> 4, h = blockIdx.y & 15;
  const float sl2e = 0.08838834764831845f * 1.44269504088896341f; // scale*log2e

  // Q fragments (A-layout): rows wave*32 + i*16 + l15, d = kd*32 + lq*8
  half8 qf[2][4];
#pragma unroll
  for (int i = 0; i < 2; i++)
#pragma unroll
    for (int kd = 0; kd < 4; kd++)
      qf[i][kd] = *(const half8*)(Q + (size_t)(b * S_ + q0 + wave * 32 + i * 16 + l15) * HID_
                                  + h * HD_ + kd * 32 + lq * 8);

  float m_i[2][4], l_i[2][4];
  floatx4 oacc[2][8];
#pragma unroll
  for (int i = 0; i < 2; i++)
#pragma unroll
    for (int r = 0; r < 4; r++) { m_i[i][r] = -3.0e38f; l_i[i][r] = 0.f; }
#pragma unroll
  for (int i = 0; i < 2; i++)
#pragma unroll
    for (int jd = 0; jd < 8; jd++) oacc[i][jd] = (floatx4){0.f, 0.f, 0.f, 0.f};

  for (int n0 = 0; n0 < S_; n0 += BN) {
    __syncthreads();  // waves done reading Ks/Vt from previous tile
    // stage K row-major (coalesced): 1024 half8 chunks
#pragma unroll
    for (int it = 0; it < 4; it++) {
      int i = it * 256 + tid;
      int r = i >> 4, dc = (i & 15) * 8;
      *(half8*)&Ks[r][dc] = *(const half8*)(K + (size_t)(b * S_ + n0 + r) * HD_ + dc);
    }
    // stage V transposed: kv-major mapping -> lanes write consecutive kv
    // (bank = lane/2 within each d-row write: 2-way, free)
#pragma unroll
    for (int it = 0; it < 4; it++) {
      int i = it * 256 + tid;
      int r = i & 63, dc = (i >> 6) * 8;
      half8 vv = *(const half8*)(V + (size_t)(b * S_ + n0 + r) * HD_ + dc);
#pragma unroll
      for (int j = 0; j < 8; j++) Vt[dc + j][r] = vv[j];
    }
    if (tid < BN) mk[tid] = mask[b * S_ + n0 + tid];
    __syncthreads();

    // ---- S = Q K^T ----
    floatx4 sc[2][4];
#pragma unroll
    for (int i = 0; i < 2; i++)
#pragma unroll
      for (int j = 0; j < 4; j++) sc[i][j] = (floatx4){0.f, 0.f, 0.f, 0.f};
#pragma unroll
    for (int kd = 0; kd < 4; kd++) {
      half8 kb[4];
#pragma unroll
      for (int j = 0; j < 4; j++)
        kb[j] = *(const half8*)&Ks[j * 16 + l15][kd * 32 + lq * 8];
#pragma unroll
      for (int i = 0; i < 2; i++)
#pragma unroll
        for (int j = 0; j < 4; j++)
          sc[i][j] = __builtin_amdgcn_mfma_f32_16x16x32_f16(qf[i][kd], kb[j], sc[i][j], 0, 0, 0);
    }

    int mkv[4];
#pragma unroll
    for (int j = 0; j < 4; j++) mkv[j] = mk[j * 16 + l15];

    // ---- online softmax (rows live in quad-groups; butterfly over 16 lanes)
    float p[2][4][4];
#pragma unroll
    for (int i = 0; i < 2; i++) {
#pragma unroll
      for (int j = 0; j < 4; j++)
#pragma unroll
        for (int r = 0; r < 4; r++) {
          float t = sc[i][j][r] * sl2e;
          p[i][j][r] = (mkv[j] != 0) ? t : -3.0e38f;
        }
#pragma unroll
      for (int r = 0; r < 4; r++) {
        float rm = fmaxf(fmaxf(p[i][0][r], p[i][1][r]), fmaxf(p[i][2][r], p[i][3][r]));
        rm = fmaxf(rm, __shfl_xor(rm, 1));
        rm = fmaxf(rm, __shfl_xor(rm, 2));
        rm = fmaxf(rm, __shfl_xor(rm, 4));
        rm = fmaxf(rm, __shfl_xor(rm, 8));
        float mnew = fmaxf(m_i[i][r], rm);
        float al   = __builtin_amdgcn_exp2f(m_i[i][r] - mnew);
        m_i[i][r]  = mnew;
        float rs = 0.f;
#pragma unroll
        for (int j = 0; j < 4; j++) {
          float pv = (mkv[j] != 0) ? __builtin_amdgcn_exp2f(p[i][j][r] - mnew) : 0.f;
          p[i][j][r] = pv;
          rs += pv;
        }
        rs += __shfl_xor(rs, 1);
        rs += __shfl_xor(rs, 2);
        rs += __shfl_xor(rs, 4);
        rs += __shfl_xor(rs, 8);
        l_i[i][r] = l_i[i][r] * al + rs;
#pragma unroll
        for (int jd = 0; jd < 8; jd++) oacc[i][jd][r] *= al;
      }
    }

    // ---- P to LDS (C-layout positions), fp16
#pragma unroll
    for (int i = 0; i < 2; i++)
#pragma unroll
      for (int j = 0; j < 4; j++)
#pragma unroll
        for (int r = 0; r < 4; r++)
          Ps[wave * 32 + i * 16 + lq * 4 + r][j * 16 + l15] = (_Float16)p[i][j][r];

    // ---- O += P V  (A-frags from Ps, B-frags from Vt; wave-private rows)
#pragma unroll
    for (int kk = 0; kk < 2; kk++) {
      half8 pa[2];
#pragma unroll
      for (int i = 0; i < 2; i++)
        pa[i] = *(const half8*)&Ps[wave * 32 + i * 16 + l15][kk * 32 + lq * 8];
#pragma unroll
      for (int jd = 0; jd < 8; jd++) {
        half8 vb = *(const half8*)&Vt[jd * 16 + l15][kk * 32 + lq * 8];
#pragma unroll
        for (int i = 0; i < 2; i++)
          oacc[i][jd] = __builtin_amdgcn_mfma_f32_16x16x32_f16(pa[i], vb, oacc[i][jd], 0, 0, 0);
      }
    }
  }

  // ---- epilogue: O / l -> fp16 attn buffer (row, h*HD+d)
#pragma unroll
  for (int i = 0; i < 2; i++)
#pragma unroll
    for (int r = 0; r < 4; r++) {
      float inv = 1.0f / l_i[i][r];
      size_t row = (size_t)(b * S_ + q0 + wave * 32 + i * 16 + lq * 4 + r);
#pragma unroll
      for (int jd = 0; jd < 8; jd++)
        Obuf[row * HID_ + h * HD_ + jd * 16 + l15] = (_Float16)(oacc[i][jd][r] * inv);
    }
}

// ---------------------------------------------------------------------------
extern "C" void kernel_launch(void* const* d_in, const int* in_sizes, int n_in,
                              void* d_out, int out_size, void* d_ws, size_t ws_size,
                              hipStream_t stream) {
  const float* hidden = (const float*)d_in[0];
  const int*   mask   = (const int*)d_in[1];
  const float* Wq = (const float*)d_in[2];
  const float* bq = (const float*)d_in[3];
  const float* Wk = (const float*)d_in[4];
  const float* bk = (const float*)d_in[5];
  const float* Wv = (const float*)d_in[6];
  const float* bv = (const float*)d_in[7];
  const float* Wo = (const float*)d_in[8];
  const float* bo = (const float*)d_in[9];
  float* out = (float*)d_out;

  char* p = (char*)d_ws;
  auto alloc = [&](size_t bytes) {
    char* r = p;
    p += (bytes + 255) & ~(size_t)255;
    return r;
  };
  _Float16* hidh  = (_Float16*)alloc((size_t)M_ * HID_ * 2);
  _Float16* Wqh   = (_Float16*)alloc((size_t)HID_ * HID_ * 2);
  _Float16* Wkh   = (_Float16*)alloc((size_t)HD_ * HID_ * 2);
  _Float16* Wvh   = (_Float16*)alloc((size_t)HD_ * HID_ * 2);
  _Float16* Woh   = (_Float16*)alloc((size_t)HID_ * HID_ * 2);
  _Float16* Qh    = (_Float16*)alloc((size_t)M_ * HID_ * 2);
  _Float16* Kh    = (_Float16*)alloc((size_t)M_ * HD_ * 2);
  _Float16* Vh    = (_Float16*)alloc((size_t)M_ * HD_ * 2);
  _Float16* attnh = (_Float16*)alloc((size_t)M_ * HID_ * 2);

  // fp32 -> fp16 casts
  {
    int n8;
    n8 = M_ * HID_ / 8;
    cvt_f16_kernel<<<(n8 + 255) / 256, 256, 0, stream>>>(hidden, hidh, n8);
    n8 = HID_ * HID_ / 8;
    cvt_f16_kernel<<<(n8 + 255) / 256, 256, 0, stream>>>(Wq, Wqh, n8);
    n8 = HD_ * HID_ / 8;
    cvt_f16_kernel<<<(n8 + 255) / 256, 256, 0, stream>>>(Wk, Wkh, n8);
    cvt_f16_kernel<<<(n8 + 255) / 256, 256, 0, stream>>>(Wv, Wvh, n8);
    n8 = HID_ * HID_ / 8;
    cvt_f16_kernel<<<(n8 + 255) / 256, 256, 0, stream>>>(Wo, Woh, n8);
  }

  // projections (fp16 outputs for Q/K/V)
  dim3 gq(HID_ / 128, M_ / 128);  // (16, 32)
  gemm_q<<<gq, 256, 0, stream>>>(hidh, Wqh, bq, Qh, HID_, HID_);
  dim3 gkv(2, M_ / 64);           // (2, 64) = 128 blocks
  gemm_kv<<<gkv, 256, 0, stream>>>(hidh, Wkh, bk, Kh, Wvh, bv, Vh);

  // attention (MFMA flash)
  dim3 ga(S_ / 128, B_ * NH_);    // (16, 32)
  attn_mfma<<<ga, 256, 0, stream>>>(Qh, Kh, Vh, mask, attnh);

  // output projection -> d_out (fp32)
  gemm_o<<<gq, 256, 0, stream>>>(attnh, Woh, bo, out, HID_, HID_);
}

// Round 5
// 443.199 us; speedup vs baseline: 4.1187x; 1.0010x over previous
//
#include <hip/hip_runtime.h>

// MQA: B=2, S=2048, HID=2048, NH=16, HD=128
#define B_   2
#define S_   2048
#define HID_ 2048
#define NH_  16
#define HD_  128
#define M_   (B_ * S_)   // 4096 total rows

using half4   = __attribute__((ext_vector_type(4))) _Float16;
using half8   = __attribute__((ext_vector_type(8))) _Float16;
using floatx4 = __attribute__((ext_vector_type(4))) float;

// async global->LDS, 16B per lane. LDS base MUST be wave-uniform; lane i
// lands at ldsbase + i*16 (guide §5: no per-lane scatter, no padding).
__device__ __forceinline__ void gl_lds16(const void* g, void* l) {
  __builtin_amdgcn_global_load_lds(
      (const __attribute__((address_space(1))) void*)g,
      (__attribute__((address_space(3))) void*)l, 16, 0, 0);
}

// ---------------------------------------------------------------------------
// fp32 -> fp16 conversion, 8 elems / thread
// ---------------------------------------------------------------------------
__global__ __launch_bounds__(256) void cvt_f16_kernel(
    const float* __restrict__ src, _Float16* __restrict__ dst, int n8) {
  int i = blockIdx.x * 256 + threadIdx.x;
  if (i >= n8) return;
  const floatx4* s = (const floatx4*)src;
  floatx4 a = s[(size_t)i * 2];
  floatx4 b = s[(size_t)i * 2 + 1];
  half8 h;
  h[0] = (_Float16)a[0]; h[1] = (_Float16)a[1];
  h[2] = (_Float16)a[2]; h[3] = (_Float16)a[3];
  h[4] = (_Float16)b[0]; h[5] = (_Float16)b[1];
  h[6] = (_Float16)b[2]; h[7] = (_Float16)b[3];
  *(half8*)(dst + (size_t)i * 8) = h;
}

// ---------------------------------------------------------------------------
// m97-style GEMM body: C[M,N] = A[M,K] @ W[N,K]^T + bias.
// 128x128 tile, BK=32, unpadded LDS, global_load_lds width=16 staging.
// 4 waves 2x2, each wave 64x64 via 4x4 MFMA 16x16x32_f16.
// ---------------------------------------------------------------------------
template <typename OutT>
__device__ __forceinline__ void gemm128_body(
    const _Float16* __restrict__ A, const _Float16* __restrict__ W,
    const float* __restrict__ bias, OutT* __restrict__ C,
    int Nout, int K, int m0, int n0w, int c0) {
  __shared__ __align__(16) _Float16 As[128][32];  // 8 KB, 64 B rows
  __shared__ __align__(16) _Float16 Ws[128][32];

  const int tid  = threadIdx.x;
  const int lane = tid & 63;
  const int wave = tid >> 6;
  const int wm   = wave >> 1, wn = wave & 1;
  const int l15  = lane & 15, lq = lane >> 4;
  // staging: lane covers row (lane>>2) within a 16-row wave chunk, col (lane&3)*8
  const int srow = wave * 16 + (lane >> 2);
  const int scol = (lane & 3) * 8;

  floatx4 acc[4][4];
#pragma unroll
  for (int i = 0; i < 4; i++)
#pragma unroll
    for (int j = 0; j < 4; j++) acc[i][j] = (floatx4){0.f, 0.f, 0.f, 0.f};

  const _Float16* Ag = A + (size_t)(m0 + srow) * K + scol;
  const _Float16* Wg = W + (size_t)(n0w + srow) * K + scol;
  const size_t step64 = (size_t)64 * K;

  for (int kt = 0; kt < K; kt += 32) {
    gl_lds16(Ag + kt,           &As[wave * 16][0]);
    gl_lds16(Ag + step64 + kt,  &As[64 + wave * 16][0]);
    gl_lds16(Wg + kt,           &Ws[wave * 16][0]);
    gl_lds16(Wg + step64 + kt,  &Ws[64 + wave * 16][0]);
    __syncthreads();

    half8 af[4], bf[4];
#pragma unroll
    for (int i = 0; i < 4; i++)
      af[i] = *(const half8*)&As[wm * 64 + i * 16 + l15][lq * 8];
#pragma unroll
    for (int j = 0; j < 4; j++)
      bf[j] = *(const half8*)&Ws[wn * 64 + j * 16 + l15][lq * 8];
#pragma unroll
    for (int i = 0; i < 4; i++)
#pragma unroll
      for (int j = 0; j < 4; j++)
        acc[i][j] = __builtin_amdgcn_mfma_f32_16x16x32_f16(af[i], bf[j], acc[i][j], 0, 0, 0);
    __syncthreads();
  }

  const int rq = lq * 4;
#pragma unroll
  for (int j = 0; j < 4; j++) {
    int col_l = wn * 64 + j * 16 + l15;
    float bv  = bias[n0w + col_l];
#pragma unroll
    for (int i = 0; i < 4; i++) {
      int row = m0 + wm * 64 + i * 16 + rq;
#pragma unroll
      for (int r = 0; r < 4; r++)
        C[(size_t)(row + r) * Nout + c0 + col_l] = (OutT)(acc[i][j][r] + bv);
    }
  }
}

// Fused Q/K/V projection: grid.x = 18 column tiles (16 Q + 1 K + 1 V)
__global__ __launch_bounds__(256) void gemm_qkv(
    const _Float16* __restrict__ A,
    const _Float16* __restrict__ Wq, const float* __restrict__ bq, _Float16* __restrict__ Qh,
    const _Float16* __restrict__ Wk, const float* __restrict__ bk, _Float16* __restrict__ Kh,
    const _Float16* __restrict__ Wv, const float* __restrict__ bv, _Float16* __restrict__ Vh) {
  const int nt = blockIdx.x, m0 = blockIdx.y * 128;
  if (nt < 16)
    gemm128_body<_Float16>(A, Wq, bq, Qh, HID_, HID_, m0, nt * 128, nt * 128);
  else if (nt == 16)
    gemm128_body<_Float16>(A, Wk, bk, Kh, HD_, HID_, m0, 0, 0);
  else
    gemm128_body<_Float16>(A, Wv, bv, Vh, HD_, HID_, m0, 0, 0);
}

__global__ __launch_bounds__(256) void gemm_out(
    const _Float16* __restrict__ A, const _Float16* __restrict__ W,
    const float* __restrict__ bias, float* __restrict__ C) {
  gemm128_body<float>(A, W, bias, C, HID_, HID_, blockIdx.y * 128,
                      blockIdx.x * 128, blockIdx.x * 128);
}

// ---------------------------------------------------------------------------
// MFMA flash attention, S^T formulation.
// Block = 128 q-rows of one (b,h); 4 waves x 32 rows (2 m-subtiles of 16).
// S^T = mfma(K_frag, Q_frag): C-layout col = q-row m (l15), row = kv n
// (lq*4+r). Softmax per m: 16 in-thread values + 2 butterflies (x16, x32).
// P^T registers are directly A-frags of mfma_f32_16x16x16f16 (k = lq*4+j),
// so no P LDS round-trip. V staged transposed -> half4 B-frags.
// alpha / 1/l broadcast to C-layout rows via __shfl from lanes 0..15.
// ---------------------------------------------------------------------------
__global__ __launch_bounds__(256) void attn_mfma(
    const _Float16* __restrict__ Q, const _Float16* __restrict__ K,
    const _Float16* __restrict__ V, const int* __restrict__ mask,
    _Float16* __restrict__ Obuf) {
  constexpr int BN = 64, KP = 136, VP = 72;
  __shared__ __align__(16) _Float16 Ks[BN][KP];   // 17.4 KB
  __shared__ __align__(16) _Float16 Vt[HD_][VP];  // 18.4 KB
  __shared__ __align__(16) float maskf[BN];       // additive mask

  const int tid  = threadIdx.x;
  const int lane = tid & 63, wave = tid >> 6;
  const int l15  = lane & 15, lq = lane >> 4;
  const int q0   = blockIdx.x * 128;
  const int b    = blockIdx.y >> 4, h = blockIdx.y & 15;
  const float sl2e = 0.08838834764831845f * 1.44269504088896341f;  // scale*log2e

  // Q fragments (B-operand of S^T mfma; layout same as A): m=l15, d=lq*8+j
  half8 qf[2][4];
#pragma unroll
  for (int i = 0; i < 2; i++)
#pragma unroll
    for (int kd = 0; kd < 4; kd++)
      qf[i][kd] = *(const half8*)(Q + (size_t)(b * S_ + q0 + wave * 32 + i * 16 + l15) * HID_
                                  + h * HD_ + kd * 32 + lq * 8);

  float m_i[2] = {-3.0e38f, -3.0e38f};
  float l_i[2] = {0.f, 0.f};
  floatx4 oacc[2][8];
#pragma unroll
  for (int i = 0; i < 2; i++)
#pragma unroll
    for (int jd = 0; jd < 8; jd++) oacc[i][jd] = (floatx4){0.f, 0.f, 0.f, 0.f};

  for (int n0 = 0; n0 < S_; n0 += BN) {
    __syncthreads();  // previous tile's reads done before overwrite
    // stage K row-major: 1024 half8 chunks
#pragma unroll
    for (int it = 0; it < 4; it++) {
      int i = it * 256 + tid;
      int r = i >> 4, dc = (i & 15) * 8;
      *(half8*)&Ks[r][dc] = *(const half8*)(K + (size_t)(b * S_ + n0 + r) * HD_ + dc);
    }
    // stage V transposed (kv-major writes: 2-way bank alias, free)
#pragma unroll
    for (int it = 0; it < 4; it++) {
      int i = it * 256 + tid;
      int r = i & 63, dc = (i >> 6) * 8;
      half8 vv = *(const half8*)(V + (size_t)(b * S_ + n0 + r) * HD_ + dc);
#pragma unroll
      for (int j = 0; j < 8; j++) Vt[dc + j][r] = vv[j];
    }
    if (tid < BN) maskf[tid] = mask[b * S_ + n0 + tid] ? 0.f : -3.0e38f;
    __syncthreads();

    // ---- S^T = K Q^T : st[j][i], n = j*16+lq*4+r, m = i*16+l15 (+wave*32)
    floatx4 st[4][2];
#pragma unroll
    for (int j = 0; j < 4; j++)
#pragma unroll
      for (int i = 0; i < 2; i++) st[j][i] = (floatx4){0.f, 0.f, 0.f, 0.f};
#pragma unroll
    for (int kd = 0; kd < 4; kd++) {
      half8 kb[4];
#pragma unroll
      for (int j = 0; j < 4; j++)
        kb[j] = *(const half8*)&Ks[j * 16 + l15][kd * 32 + lq * 8];
#pragma unroll
      for (int j = 0; j < 4; j++)
#pragma unroll
        for (int i = 0; i < 2; i++)
          st[j][i] = __builtin_amdgcn_mfma_f32_16x16x32_f16(kb[j], qf[i][kd], st[j][i], 0, 0, 0);
    }

    floatx4 amf[4];
#pragma unroll
    for (int j = 0; j < 4; j++)
      amf[j] = *(const floatx4*)&maskf[j * 16 + lq * 4];

    // ---- online softmax + rescale + PV fragments
    half4 ph[2][4];
#pragma unroll
    for (int i = 0; i < 2; i++) {
      float mx = -3.0e38f;
#pragma unroll
      for (int j = 0; j < 4; j++)
#pragma unroll
        for (int r = 0; r < 4; r++) {
          float t = st[j][i][r] * sl2e + amf[j][r];
          st[j][i][r] = t;
          mx = fmaxf(mx, t);
        }
      mx = fmaxf(mx, __shfl_xor(mx, 16));
      mx = fmaxf(mx, __shfl_xor(mx, 32));
      float mnew  = fmaxf(m_i[i], mx);
      float alpha = __builtin_amdgcn_exp2f(m_i[i] - mnew);
      m_i[i] = mnew;
      float rs = 0.f;
#pragma unroll
      for (int j = 0; j < 4; j++)
#pragma unroll
        for (int r = 0; r < 4; r++) {
          float pv = __builtin_amdgcn_exp2f(st[j][i][r] - mnew);
          ph[i][j][r] = (_Float16)pv;
          rs += pv;
        }
      rs += __shfl_xor(rs, 16);
      rs += __shfl_xor(rs, 32);
      l_i[i] = l_i[i] * alpha + rs;
      // broadcast alpha (held for m=l15) to C-layout rows m=lq*4+r
#pragma unroll
      for (int r = 0; r < 4; r++) {
        float a_r = __shfl(alpha, lq * 4 + r);
#pragma unroll
        for (int jd = 0; jd < 8; jd++) oacc[i][jd][r] *= a_r;
      }
    }

    // ---- O += P V via 16x16x16 (A = ph in-register, B = Vt half4)
#pragma unroll
    for (int j = 0; j < 4; j++) {
#pragma unroll
      for (int jd = 0; jd < 8; jd++) {
        half4 vb = *(const half4*)&Vt[jd * 16 + l15][j * 16 + lq * 4];
#pragma unroll
        for (int i = 0; i < 2; i++)
          oacc[i][jd] = __builtin_amdgcn_mfma_f32_16x16x16f16(ph[i][j], vb, oacc[i][jd], 0, 0, 0);
      }
    }
  }

  // ---- epilogue: O rows m = i*16+lq*4+r, cols d = jd*16+l15
#pragma unroll
  for (int i = 0; i < 2; i++) {
    float linv = 1.0f / l_i[i];
#pragma unroll
    for (int r = 0; r < 4; r++) {
      float lr = __shfl(linv, lq * 4 + r);
      size_t row = (size_t)(b * S_ + q0 + wave * 32 + i * 16 + lq * 4 + r);
#pragma unroll
      for (int jd = 0; jd < 8; jd++)
        Obuf[row * HID_ + h * HD_ + jd * 16 + l15] = (_Float16)(oacc[i][jd][r] * lr);
    }
  }
}

// ---------------------------------------------------------------------------
extern "C" void kernel_launch(void* const* d_in, const int* in_sizes, int n_in,
                              void* d_out, int out_size, void* d_ws, size_t ws_size,
                              hipStream_t stream) {
  const float* hidden = (const float*)d_in[0];
  const int*   mask   = (const int*)d_in[1];
  const float* Wq = (const float*)d_in[2];
  const float* bq = (const float*)d_in[3];
  const float* Wk = (const float*)d_in[4];
  const float* bk = (const float*)d_in[5];
  const float* Wv = (const float*)d_in[6];
  const float* bv = (const float*)d_in[7];
  const float* Wo = (const float*)d_in[8];
  const float* bo = (const float*)d_in[9];
  float* out = (float*)d_out;

  char* p = (char*)d_ws;
  auto alloc = [&](size_t bytes) {
    char* r = p;
    p += (bytes + 255) & ~(size_t)255;
    return r;
  };
  _Float16* hidh  = (_Float16*)alloc((size_t)M_ * HID_ * 2);
  _Float16* Wqh   = (_Float16*)alloc((size_t)HID_ * HID_ * 2);
  _Float16* Wkh   = (_Float16*)alloc((size_t)HD_ * HID_ * 2);
  _Float16* Wvh   = (_Float16*)alloc((size_t)HD_ * HID_ * 2);
  _Float16* Woh   = (_Float16*)alloc((size_t)HID_ * HID_ * 2);
  _Float16* Qh    = (_Float16*)alloc((size_t)M_ * HID_ * 2);
  _Float16* Kh    = (_Float16*)alloc((size_t)M_ * HD_ * 2);
  _Float16* Vh    = (_Float16*)alloc((size_t)M_ * HD_ * 2);
  _Float16* attnh = (_Float16*)alloc((size_t)M_ * HID_ * 2);

  // fp32 -> fp16 casts
  {
    int n8;
    n8 = M_ * HID_ / 8;
    cvt_f16_kernel<<<(n8 + 255) / 256, 256, 0, stream>>>(hidden, hidh, n8);
    n8 = HID_ * HID_ / 8;
    cvt_f16_kernel<<<(n8 + 255) / 256, 256, 0, stream>>>(Wq, Wqh, n8);
    n8 = HD_ * HID_ / 8;
    cvt_f16_kernel<<<(n8 + 255) / 256, 256, 0, stream>>>(Wk, Wkh, n8);
    cvt_f16_kernel<<<(n8 + 255) / 256, 256, 0, stream>>>(Wv, Wvh, n8);
    n8 = HID_ * HID_ / 8;
    cvt_f16_kernel<<<(n8 + 255) / 256, 256, 0, stream>>>(Wo, Woh, n8);
  }

  // fused Q/K/V projection: 18 column tiles x 32 row tiles
  dim3 gqkv(18, M_ / 128);
  gemm_qkv<<<gqkv, 256, 0, stream>>>(hidh, Wqh, bq, Qh, Wkh, bk, Kh, Wvh, bv, Vh);

  // attention (S^T flash)
  dim3 ga(S_ / 128, B_ * NH_);  // (16, 32)
  attn_mfma<<<ga, 256, 0, stream>>>(Qh, Kh, Vh, mask, attnh);

  // output projection -> d_out (fp32)
  dim3 go(HID_ / 128, M_ / 128);
  gemm_out<<<go, 256, 0, stream>>>(attnh, Woh, bo, out);
}

// Round 6
// 400.209 us; speedup vs baseline: 4.5611x; 1.1074x over previous
//
#include <hip/hip_runtime.h>

// MQA: B=2, S=2048, HID=2048, NH=16, HD=128
#define B_   2
#define S_   2048
#define HID_ 2048
#define NH_  16
#define HD_  128
#define M_   (B_ * S_)   // 4096 total rows

using half4   = __attribute__((ext_vector_type(4))) _Float16;
using half8   = __attribute__((ext_vector_type(8))) _Float16;
using floatx4 = __attribute__((ext_vector_type(4))) float;

// async global->LDS, 16B per lane (LDS dst = wave-uniform base + lane*16)
__device__ __forceinline__ void gl_lds16(const void* g, void* l) {
  __builtin_amdgcn_global_load_lds(
      (const __attribute__((address_space(1))) void*)g,
      (__attribute__((address_space(3))) void*)l, 16, 0, 0);
}

__device__ __forceinline__ void cvt8(const float* s, _Float16* d, int i) {
  const floatx4* sp = (const floatx4*)s;
  floatx4 a = sp[(size_t)i * 2];
  floatx4 b = sp[(size_t)i * 2 + 1];
  half8 h;
  h[0] = (_Float16)a[0]; h[1] = (_Float16)a[1];
  h[2] = (_Float16)a[2]; h[3] = (_Float16)a[3];
  h[4] = (_Float16)b[0]; h[5] = (_Float16)b[1];
  h[6] = (_Float16)b[2]; h[7] = (_Float16)b[3];
  *(half8*)(d + (size_t)i * 8) = h;
}

// ---------------------------------------------------------------------------
// One fused fp32->fp16 cast for hidden + all 4 weights.
// Block ranges: hid 4096, Wq 2048, Wk 128, Wv 128, Wo 2048  (2048 elems/blk)
// ---------------------------------------------------------------------------
__global__ __launch_bounds__(256) void cvt_all(
    const float* __restrict__ h,  const float* __restrict__ wq,
    const float* __restrict__ wk, const float* __restrict__ wv,
    const float* __restrict__ wo,
    _Float16* __restrict__ dh,  _Float16* __restrict__ dwq,
    _Float16* __restrict__ dwk, _Float16* __restrict__ dwv,
    _Float16* __restrict__ dwo) {
  int bid = blockIdx.x;
  const float* s;
  _Float16* d;
  int off;
  if (bid < 4096)      { s = h;  d = dh;  off = bid; }
  else if (bid < 6144) { s = wq; d = dwq; off = bid - 4096; }
  else if (bid < 6272) { s = wk; d = dwk; off = bid - 6144; }
  else if (bid < 6400) { s = wv; d = dwv; off = bid - 6272; }
  else                 { s = wo; d = dwo; off = bid - 6400; }
  cvt8(s, d, off * 256 + threadIdx.x);
}

// ---------------------------------------------------------------------------
// V^T precompute: Vh[M][HD] -> VhT[B][HD][S]  (64x64 LDS tile transpose)
// ---------------------------------------------------------------------------
__global__ __launch_bounds__(256) void transpose_v(
    const _Float16* __restrict__ Vh, _Float16* __restrict__ VhT) {
  __shared__ _Float16 t[64][72];
  const int tid = threadIdx.x;
  const int s0  = blockIdx.x * 64;  // over M_ rows; 64 | S_ so no b straddle
  const int d0  = blockIdx.y * 64;
  const int b   = s0 / S_;
  const int sl  = s0 % S_;
#pragma unroll
  for (int it = 0; it < 2; it++) {
    int i = it * 256 + tid;
    int r = i >> 3, c = (i & 7) * 8;
    *(half8*)&t[r][c] = *(const half8*)(Vh + (size_t)(s0 + r) * HD_ + d0 + c);
  }
  __syncthreads();
#pragma unroll
  for (int it = 0; it < 2; it++) {
    int i = it * 256 + tid;
    int dl = i >> 3, cs = (i & 7) * 8;
    half8 o;
#pragma unroll
    for (int j = 0; j < 8; j++) o[j] = t[cs + j][dl];
    *(half8*)(VhT + (size_t)b * HD_ * S_ + (size_t)(d0 + dl) * S_ + sl + cs) = o;
  }
}

// ---------------------------------------------------------------------------
// m97-style GEMM body: C[M,N] = A[M,K] @ W[N,K]^T + bias.
// 128x128 tile, BK=32, unpadded LDS, global_load_lds width=16 staging.
// ---------------------------------------------------------------------------
template <typename OutT>
__device__ __forceinline__ void gemm128_body(
    const _Float16* __restrict__ A, const _Float16* __restrict__ W,
    const float* __restrict__ bias, OutT* __restrict__ C,
    int Nout, int K, int m0, int n0w, int c0) {
  __shared__ __align__(16) _Float16 As[128][32];  // 8 KB, 64 B rows
  __shared__ __align__(16) _Float16 Ws[128][32];

  const int tid  = threadIdx.x;
  const int lane = tid & 63;
  const int wave = tid >> 6;
  const int wm   = wave >> 1, wn = wave & 1;
  const int l15  = lane & 15, lq = lane >> 4;
  const int srow = wave * 16 + (lane >> 2);
  const int scol = (lane & 3) * 8;

  floatx4 acc[4][4];
#pragma unroll
  for (int i = 0; i < 4; i++)
#pragma unroll
    for (int j = 0; j < 4; j++) acc[i][j] = (floatx4){0.f, 0.f, 0.f, 0.f};

  const _Float16* Ag = A + (size_t)(m0 + srow) * K + scol;
  const _Float16* Wg = W + (size_t)(n0w + srow) * K + scol;
  const size_t step64 = (size_t)64 * K;

  for (int kt = 0; kt < K; kt += 32) {
    gl_lds16(Ag + kt,          &As[wave * 16][0]);
    gl_lds16(Ag + step64 + kt, &As[64 + wave * 16][0]);
    gl_lds16(Wg + kt,          &Ws[wave * 16][0]);
    gl_lds16(Wg + step64 + kt, &Ws[64 + wave * 16][0]);
    __syncthreads();

    half8 af[4], bf[4];
#pragma unroll
    for (int i = 0; i < 4; i++)
      af[i] = *(const half8*)&As[wm * 64 + i * 16 + l15][lq * 8];
#pragma unroll
    for (int j = 0; j < 4; j++)
      bf[j] = *(const half8*)&Ws[wn * 64 + j * 16 + l15][lq * 8];
#pragma unroll
    for (int i = 0; i < 4; i++)
#pragma unroll
      for (int j = 0; j < 4; j++)
        acc[i][j] = __builtin_amdgcn_mfma_f32_16x16x32_f16(af[i], bf[j], acc[i][j], 0, 0, 0);
    __syncthreads();
  }

  const int rq = lq * 4;
#pragma unroll
  for (int j = 0; j < 4; j++) {
    int col_l = wn * 64 + j * 16 + l15;
    float bv  = bias[n0w + col_l];
#pragma unroll
    for (int i = 0; i < 4; i++) {
      int row = m0 + wm * 64 + i * 16 + rq;
#pragma unroll
      for (int r = 0; r < 4; r++)
        C[(size_t)(row + r) * Nout + c0 + col_l] = (OutT)(acc[i][j][r] + bv);
    }
  }
}

// Fused Q/K/V projection: grid.x = 18 column tiles (16 Q + 1 K + 1 V)
__global__ __launch_bounds__(256) void gemm_qkv(
    const _Float16* __restrict__ A,
    const _Float16* __restrict__ Wq, const float* __restrict__ bq, _Float16* __restrict__ Qh,
    const _Float16* __restrict__ Wk, const float* __restrict__ bk, _Float16* __restrict__ Kh,
    const _Float16* __restrict__ Wv, const float* __restrict__ bv, _Float16* __restrict__ Vh) {
  const int nt = blockIdx.x, m0 = blockIdx.y * 128;
  if (nt < 16)
    gemm128_body<_Float16>(A, Wq, bq, Qh, HID_, HID_, m0, nt * 128, nt * 128);
  else if (nt == 16)
    gemm128_body<_Float16>(A, Wk, bk, Kh, HD_, HID_, m0, 0, 0);
  else
    gemm128_body<_Float16>(A, Wv, bv, Vh, HD_, HID_, m0, 0, 0);
}

__global__ __launch_bounds__(256) void gemm_out(
    const _Float16* __restrict__ A, const _Float16* __restrict__ W,
    const float* __restrict__ bias, float* __restrict__ C) {
  gemm128_body<float>(A, W, bias, C, HID_, HID_, blockIdx.y * 128,
                      blockIdx.x * 128, blockIdx.x * 128);
}

// ---------------------------------------------------------------------------
// MFMA flash attention, S^T formulation (round-5 structure) with:
//  - V staged from precomputed VhT via ds_write_b128 (no per-tile transpose)
//  - __launch_bounds__(256,2) to pin VGPR <= 128
// ---------------------------------------------------------------------------
__global__ __launch_bounds__(256, 2) void attn_mfma(
    const _Float16* __restrict__ Q, const _Float16* __restrict__ K,
    const _Float16* __restrict__ VhT, const int* __restrict__ mask,
    _Float16* __restrict__ Obuf) {
  constexpr int BN = 64, KP = 136, VP = 72;
  __shared__ __align__(16) _Float16 Ks[BN][KP];   // 17.4 KB
  __shared__ __align__(16) _Float16 Vt[HD_][VP];  // 18.4 KB
  __shared__ __align__(16) float maskf[BN];

  const int tid  = threadIdx.x;
  const int lane = tid & 63, wave = tid >> 6;
  const int l15  = lane & 15, lq = lane >> 4;
  const int q0   = blockIdx.x * 128;
  const int b    = blockIdx.y >> 4, h = blockIdx.y & 15;
  const float sl2e = 0.08838834764831845f * 1.44269504088896341f;  // scale*log2e
  const _Float16* VT = VhT + (size_t)b * HD_ * S_;

  // Q fragments (B-operand of S^T mfma): m=l15, d=lq*8+j
  half8 qf[2][4];
#pragma unroll
  for (int i = 0; i < 2; i++)
#pragma unroll
    for (int kd = 0; kd < 4; kd++)
      qf[i][kd] = *(const half8*)(Q + (size_t)(b * S_ + q0 + wave * 32 + i * 16 + l15) * HID_
                                  + h * HD_ + kd * 32 + lq * 8);

  float m_i[2] = {-3.0e38f, -3.0e38f};
  float l_i[2] = {0.f, 0.f};
  floatx4 oacc[2][8];
#pragma unroll
  for (int i = 0; i < 2; i++)
#pragma unroll
    for (int jd = 0; jd < 8; jd++) oacc[i][jd] = (floatx4){0.f, 0.f, 0.f, 0.f};

  for (int n0 = 0; n0 < S_; n0 += BN) {
    __syncthreads();
    // stage K row-major: 1024 half8 chunks
#pragma unroll
    for (int it = 0; it < 4; it++) {
      int i = it * 256 + tid;
      int r = i >> 4, dc = (i & 15) * 8;
      *(half8*)&Ks[r][dc] = *(const half8*)(K + (size_t)(b * S_ + n0 + r) * HD_ + dc);
    }
    // stage V^T rows (d-major, contiguous kv): 1024 half8 chunks
#pragma unroll
    for (int it = 0; it < 4; it++) {
      int i = it * 256 + tid;
      int r = i >> 3, c = (i & 7) * 8;
      *(half8*)&Vt[r][c] = *(const half8*)(VT + (size_t)r * S_ + n0 + c);
    }
    if (tid < BN) maskf[tid] = mask[b * S_ + n0 + tid] ? 0.f : -3.0e38f;
    __syncthreads();

    // ---- S^T = K Q^T : st[j][i], n = j*16+lq*4+r, m = i*16+l15 (+wave*32)
    floatx4 st[4][2];
#pragma unroll
    for (int j = 0; j < 4; j++)
#pragma unroll
      for (int i = 0; i < 2; i++) st[j][i] = (floatx4){0.f, 0.f, 0.f, 0.f};
#pragma unroll
    for (int kd = 0; kd < 4; kd++) {
      half8 kb[4];
#pragma unroll
      for (int j = 0; j < 4; j++)
        kb[j] = *(const half8*)&Ks[j * 16 + l15][kd * 32 + lq * 8];
#pragma unroll
      for (int j = 0; j < 4; j++)
#pragma unroll
        for (int i = 0; i < 2; i++)
          st[j][i] = __builtin_amdgcn_mfma_f32_16x16x32_f16(kb[j], qf[i][kd], st[j][i], 0, 0, 0);
    }

    floatx4 amf[4];
#pragma unroll
    for (int j = 0; j < 4; j++)
      amf[j] = *(const floatx4*)&maskf[j * 16 + lq * 4];

    // ---- online softmax (per q-row m: 16 in-thread + 2 butterflies)
    half4 ph[2][4];
#pragma unroll
    for (int i = 0; i < 2; i++) {
      float mx = -3.0e38f;
#pragma unroll
      for (int j = 0; j < 4; j++)
#pragma unroll
        for (int r = 0; r < 4; r++) {
          float t = st[j][i][r] * sl2e + amf[j][r];
          st[j][i][r] = t;
          mx = fmaxf(mx, t);
        }
      mx = fmaxf(mx, __shfl_xor(mx, 16));
      mx = fmaxf(mx, __shfl_xor(mx, 32));
      float mnew  = fmaxf(m_i[i], mx);
      float alpha = __builtin_amdgcn_exp2f(m_i[i] - mnew);
      m_i[i] = mnew;
      float rs = 0.f;
#pragma unroll
      for (int j = 0; j < 4; j++)
#pragma unroll
        for (int r = 0; r < 4; r++) {
          float pv = __builtin_amdgcn_exp2f(st[j][i][r] - mnew);
          ph[i][j][r] = (_Float16)pv;
          rs += pv;
        }
      rs += __shfl_xor(rs, 16);
      rs += __shfl_xor(rs, 32);
      l_i[i] = l_i[i] * alpha + rs;
#pragma unroll
      for (int r = 0; r < 4; r++) {
        float a_r = __shfl(alpha, lq * 4 + r);
#pragma unroll
        for (int jd = 0; jd < 8; jd++) oacc[i][jd][r] *= a_r;
      }
    }

    // ---- O += P V via 16x16x16 (A = ph in-register, B = Vt half4)
#pragma unroll
    for (int j = 0; j < 4; j++) {
#pragma unroll
      for (int jd = 0; jd < 8; jd++) {
        half4 vb = *(const half4*)&Vt[jd * 16 + l15][j * 16 + lq * 4];
#pragma unroll
        for (int i = 0; i < 2; i++)
          oacc[i][jd] = __builtin_amdgcn_mfma_f32_16x16x16f16(ph[i][j], vb, oacc[i][jd], 0, 0, 0);
      }
    }
  }

  // ---- epilogue
#pragma unroll
  for (int i = 0; i < 2; i++) {
    float linv = 1.0f / l_i[i];
#pragma unroll
    for (int r = 0; r < 4; r++) {
      float lr = __shfl(linv, lq * 4 + r);
      size_t row = (size_t)(b * S_ + q0 + wave * 32 + i * 16 + lq * 4 + r);
#pragma unroll
      for (int jd = 0; jd < 8; jd++)
        Obuf[row * HID_ + h * HD_ + jd * 16 + l15] = (_Float16)(oacc[i][jd][r] * lr);
    }
  }
}

// ---------------------------------------------------------------------------
extern "C" void kernel_launch(void* const* d_in, const int* in_sizes, int n_in,
                              void* d_out, int out_size, void* d_ws, size_t ws_size,
                              hipStream_t stream) {
  const float* hidden = (const float*)d_in[0];
  const int*   mask   = (const int*)d_in[1];
  const float* Wq = (const float*)d_in[2];
  const float* bq = (const float*)d_in[3];
  const float* Wk = (const float*)d_in[4];
  const float* bk = (const float*)d_in[5];
  const float* Wv = (const float*)d_in[6];
  const float* bv = (const float*)d_in[7];
  const float* Wo = (const float*)d_in[8];
  const float* bo = (const float*)d_in[9];
  float* out = (float*)d_out;

  char* p = (char*)d_ws;
  auto alloc = [&](size_t bytes) {
    char* r = p;
    p += (bytes + 255) & ~(size_t)255;
    return r;
  };
  _Float16* hidh = (_Float16*)alloc((size_t)M_ * HID_ * 2);
  _Float16* Wqh  = (_Float16*)alloc((size_t)HID_ * HID_ * 2);
  _Float16* Wkh  = (_Float16*)alloc((size_t)HD_ * HID_ * 2);
  _Float16* Wvh  = (_Float16*)alloc((size_t)HD_ * HID_ * 2);
  _Float16* Woh  = (_Float16*)alloc((size_t)HID_ * HID_ * 2);
  _Float16* Qh   = (_Float16*)alloc((size_t)M_ * HID_ * 2);
  _Float16* Kh   = (_Float16*)alloc((size_t)M_ * HD_ * 2);
  _Float16* Vh   = (_Float16*)alloc((size_t)M_ * HD_ * 2);
  _Float16* VhT  = (_Float16*)alloc((size_t)M_ * HD_ * 2);
  _Float16* attnh = (_Float16*)alloc((size_t)M_ * HID_ * 2);

  // one fused fp32 -> fp16 cast (8448 blocks)
  cvt_all<<<8448, 256, 0, stream>>>(hidden, Wq, Wk, Wv, Wo,
                                    hidh, Wqh, Wkh, Wvh, Woh);

  // fused Q/K/V projection: 18 column tiles x 32 row tiles
  dim3 gqkv(18, M_ / 128);
  gemm_qkv<<<gqkv, 256, 0, stream>>>(hidh, Wqh, bq, Qh, Wkh, bk, Kh, Wvh, bv, Vh);

  // V^T precompute
  dim3 gt(M_ / 64, HD_ / 64);
  transpose_v<<<gt, 256, 0, stream>>>(Vh, VhT);

  // attention (S^T flash, VhT input)
  dim3 ga(S_ / 128, B_ * NH_);  // (16, 32)
  attn_mfma<<<ga, 256, 0, stream>>>(Qh, Kh, VhT, mask, attnh);

  // output projection -> d_out (fp32)
  dim3 go(HID_ / 128, M_ / 128);
  gemm_out<<<go, 256, 0, stream>>>(attnh, Woh, bo, out);
}

// Round 7
// 327.103 us; speedup vs baseline: 5.5805x; 1.2235x over previous
//
#include <hip/hip_runtime.h>

// MQA: B=2, S=2048, HID=2048, NH=16, HD=128
#define B_   2
#define S_   2048
#define HID_ 2048
#define NH_  16
#define HD_  128
#define M_   (B_ * S_)   // 4096 total rows

using half4   = __attribute__((ext_vector_type(4))) _Float16;
using half8   = __attribute__((ext_vector_type(8))) _Float16;
using floatx4 = __attribute__((ext_vector_type(4))) float;

// async global->LDS, 16B per lane (LDS dst = wave-uniform base + lane*16)
__device__ __forceinline__ void gl_lds16(const void* g, void* l) {
  __builtin_amdgcn_global_load_lds(
      (const __attribute__((address_space(1))) void*)g,
      (__attribute__((address_space(3))) void*)l, 16, 0, 0);
}

__device__ __forceinline__ void cvt8(const float* s, _Float16* d, int i) {
  const floatx4* sp = (const floatx4*)s;
  floatx4 a = sp[(size_t)i * 2];
  floatx4 b = sp[(size_t)i * 2 + 1];
  half8 h;
  h[0] = (_Float16)a[0]; h[1] = (_Float16)a[1];
  h[2] = (_Float16)a[2]; h[3] = (_Float16)a[3];
  h[4] = (_Float16)b[0]; h[5] = (_Float16)b[1];
  h[6] = (_Float16)b[2]; h[7] = (_Float16)b[3];
  *(half8*)(d + (size_t)i * 8) = h;
}

// ---------------------------------------------------------------------------
// One fused fp32->fp16 cast for hidden + all 4 weights (2048 elems/blk)
// ---------------------------------------------------------------------------
__global__ __launch_bounds__(256) void cvt_all(
    const float* __restrict__ h,  const float* __restrict__ wq,
    const float* __restrict__ wk, const float* __restrict__ wv,
    const float* __restrict__ wo,
    _Float16* __restrict__ dh,  _Float16* __restrict__ dwq,
    _Float16* __restrict__ dwk, _Float16* __restrict__ dwv,
    _Float16* __restrict__ dwo) {
  int bid = blockIdx.x;
  const float* s;
  _Float16* d;
  int off;
  if (bid < 4096)      { s = h;  d = dh;  off = bid; }
  else if (bid < 6144) { s = wq; d = dwq; off = bid - 4096; }
  else if (bid < 6272) { s = wk; d = dwk; off = bid - 6144; }
  else if (bid < 6400) { s = wv; d = dwv; off = bid - 6272; }
  else                 { s = wo; d = dwo; off = bid - 6400; }
  cvt8(s, d, off * 256 + threadIdx.x);
}

// ---------------------------------------------------------------------------
// m97-style GEMM body: C[M,N] = A[M,K] @ W[N,K]^T + bias.
// 128x128 tile, BK=32, unpadded LDS, global_load_lds width=16 staging.
// TRANS: store transposed as C[b][col][s] (for V^T), half4 per (i,j).
// ---------------------------------------------------------------------------
template <typename OutT, bool TRANS>
__device__ __forceinline__ void gemm128_body(
    const _Float16* __restrict__ A, const _Float16* __restrict__ W,
    const float* __restrict__ bias, OutT* __restrict__ C,
    int Nout, int K, int m0, int n0w, int c0) {
  __shared__ __align__(16) _Float16 As[128][32];  // 8 KB, 64 B rows
  __shared__ __align__(16) _Float16 Ws[128][32];

  const int tid  = threadIdx.x;
  const int lane = tid & 63;
  const int wave = tid >> 6;
  const int wm   = wave >> 1, wn = wave & 1;
  const int l15  = lane & 15, lq = lane >> 4;
  const int srow = wave * 16 + (lane >> 2);
  const int scol = (lane & 3) * 8;

  floatx4 acc[4][4];
#pragma unroll
  for (int i = 0; i < 4; i++)
#pragma unroll
    for (int j = 0; j < 4; j++) acc[i][j] = (floatx4){0.f, 0.f, 0.f, 0.f};

  const _Float16* Ag = A + (size_t)(m0 + srow) * K + scol;
  const _Float16* Wg = W + (size_t)(n0w + srow) * K + scol;
  const size_t step64 = (size_t)64 * K;

  for (int kt = 0; kt < K; kt += 32) {
    gl_lds16(Ag + kt,          &As[wave * 16][0]);
    gl_lds16(Ag + step64 + kt, &As[64 + wave * 16][0]);
    gl_lds16(Wg + kt,          &Ws[wave * 16][0]);
    gl_lds16(Wg + step64 + kt, &Ws[64 + wave * 16][0]);
    __syncthreads();

    half8 af[4], bf[4];
#pragma unroll
    for (int i = 0; i < 4; i++)
      af[i] = *(const half8*)&As[wm * 64 + i * 16 + l15][lq * 8];
#pragma unroll
    for (int j = 0; j < 4; j++)
      bf[j] = *(const half8*)&Ws[wn * 64 + j * 16 + l15][lq * 8];
#pragma unroll
    for (int i = 0; i < 4; i++)
#pragma unroll
      for (int j = 0; j < 4; j++)
        acc[i][j] = __builtin_amdgcn_mfma_f32_16x16x32_f16(af[i], bf[j], acc[i][j], 0, 0, 0);
    __syncthreads();
  }

  const int rq = lq * 4;
  if constexpr (TRANS) {
    // V^T epilogue: C layout [b][d=col][s], tile never straddles b (S_%128==0)
    const int b  = m0 / S_;
    const int sb = m0 - b * S_ + wm * 64;
#pragma unroll
    for (int j = 0; j < 4; j++) {
      int col  = wn * 64 + j * 16 + l15;
      float bv = bias[n0w + col];
#pragma unroll
      for (int i = 0; i < 4; i++) {
        half4 o;
#pragma unroll
        for (int r = 0; r < 4; r++) o[r] = (_Float16)(acc[i][j][r] + bv);
        *(half4*)((_Float16*)C + (size_t)b * HD_ * S_ + (size_t)col * S_
                  + sb + i * 16 + rq) = o;
      }
    }
  } else {
#pragma unroll
    for (int j = 0; j < 4; j++) {
      int col_l = wn * 64 + j * 16 + l15;
      float bv  = bias[n0w + col_l];
#pragma unroll
      for (int i = 0; i < 4; i++) {
        int row = m0 + wm * 64 + i * 16 + rq;
#pragma unroll
        for (int r = 0; r < 4; r++)
          C[(size_t)(row + r) * Nout + c0 + col_l] = (OutT)(acc[i][j][r] + bv);
      }
    }
  }
}

// Fused Q/K/V projection: grid.x = 18 column tiles (16 Q + 1 K + 1 V->V^T)
__global__ __launch_bounds__(256) void gemm_qkv(
    const _Float16* __restrict__ A,
    const _Float16* __restrict__ Wq, const float* __restrict__ bq, _Float16* __restrict__ Qh,
    const _Float16* __restrict__ Wk, const float* __restrict__ bk, _Float16* __restrict__ Kh,
    const _Float16* __restrict__ Wv, const float* __restrict__ bv, _Float16* __restrict__ VhT) {
  const int nt = blockIdx.x, m0 = blockIdx.y * 128;
  if (nt < 16)
    gemm128_body<_Float16, false>(A, Wq, bq, Qh, HID_, HID_, m0, nt * 128, nt * 128);
  else if (nt == 16)
    gemm128_body<_Float16, false>(A, Wk, bk, Kh, HD_, HID_, m0, 0, 0);
  else
    gemm128_body<_Float16, true>(A, Wv, bv, VhT, HD_, HID_, m0, 0, 0);
}

__global__ __launch_bounds__(256) void gemm_out(
    const _Float16* __restrict__ A, const _Float16* __restrict__ W,
    const float* __restrict__ bias, float* __restrict__ C) {
  gemm128_body<float, false>(A, W, bias, C, HID_, HID_, blockIdx.y * 128,
                             blockIdx.x * 128, blockIdx.x * 128);
}

// ---------------------------------------------------------------------------
// MFMA flash attention, S^T formulation, double-buffered K/V LDS:
// one barrier per KV tile; global loads for tile t+1 prefetched into
// registers before computing tile t; ds_writes to the alternate buffer.
// Mask handled via per-tile int4 register loads (no LDS).
// ---------------------------------------------------------------------------
__global__ __launch_bounds__(256, 2) void attn_mfma(
    const _Float16* __restrict__ Q, const _Float16* __restrict__ K,
    const _Float16* __restrict__ VhT, const int* __restrict__ mask,
    _Float16* __restrict__ Obuf) {
  constexpr int BN = 64, KP = 136, VP = 72, NT = S_ / BN;
  __shared__ __align__(16) _Float16 Ks[2][BN][KP];   // 34.8 KB
  __shared__ __align__(16) _Float16 Vt[2][HD_][VP];  // 36.9 KB

  const int tid  = threadIdx.x;
  const int lane = tid & 63, wave = tid >> 6;
  const int l15  = lane & 15, lq = lane >> 4;
  const int q0   = blockIdx.x * 128;
  const int b    = blockIdx.y >> 4, h = blockIdx.y & 15;
  const float sl2e = 0.08838834764831845f * 1.44269504088896341f;  // scale*log2e
  const _Float16* VT = VhT + (size_t)b * HD_ * S_;
  const _Float16* Kb = K + (size_t)b * S_ * HD_;
  const int* mb = mask + b * S_;

  // staging geometry (4 chunks each for K and V per thread)
  int krow[4], kcol[4], vrow[4], vcol[4];
#pragma unroll
  for (int it = 0; it < 4; it++) {
    int i = it * 256 + tid;
    krow[it] = i >> 4;       kcol[it] = (i & 15) * 8;
    vrow[it] = i >> 3;       vcol[it] = (i & 7) * 8;
  }

  // Q fragments (B-operand of S^T mfma): m=l15, d=lq*8+j
  half8 qf[2][4];
#pragma unroll
  for (int i = 0; i < 2; i++)
#pragma unroll
    for (int kd = 0; kd < 4; kd++)
      qf[i][kd] = *(const half8*)(Q + (size_t)(b * S_ + q0 + wave * 32 + i * 16 + l15) * HID_
                                  + h * HD_ + kd * 32 + lq * 8);

  float m_i[2] = {-3.0e38f, -3.0e38f};
  float l_i[2] = {0.f, 0.f};
  floatx4 oacc[2][8];
#pragma unroll
  for (int i = 0; i < 2; i++)
#pragma unroll
    for (int jd = 0; jd < 8; jd++) oacc[i][jd] = (floatx4){0.f, 0.f, 0.f, 0.f};

  half8 kreg[4], vreg[4];
  // prologue: tile 0 -> regs -> buf 0
#pragma unroll
  for (int it = 0; it < 4; it++) {
    kreg[it] = *(const half8*)(Kb + (size_t)krow[it] * HD_ + kcol[it]);
    vreg[it] = *(const half8*)(VT + (size_t)vrow[it] * S_ + vcol[it]);
  }
#pragma unroll
  for (int it = 0; it < 4; it++) {
    *(half8*)&Ks[0][krow[it]][kcol[it]] = kreg[it];
    *(half8*)&Vt[0][vrow[it]][vcol[it]] = vreg[it];
  }
  __syncthreads();

  for (int t = 0; t < NT; t++) {
    const int cur = t & 1;
    const int n0  = t * BN;
    const bool has_next = (t + 1) < NT;

    // prefetch tile t+1 into registers (drains during compute)
    if (has_next) {
      const int nn = n0 + BN;
#pragma unroll
      for (int it = 0; it < 4; it++) {
        kreg[it] = *(const half8*)(Kb + (size_t)(nn + krow[it]) * HD_ + kcol[it]);
        vreg[it] = *(const half8*)(VT + (size_t)vrow[it] * S_ + nn + vcol[it]);
      }
    }

    // mask for this tile: int4 per j at n = n0 + j*16 + lq*4
    int4 mk4[4];
#pragma unroll
    for (int j = 0; j < 4; j++)
      mk4[j] = *(const int4*)(mb + n0 + j * 16 + lq * 4);

    // ---- S^T = K Q^T : st[j][i], n = j*16+lq*4+r, m = i*16+l15 (+wave*32)
    floatx4 st[4][2];
#pragma unroll
    for (int j = 0; j < 4; j++)
#pragma unroll
      for (int i = 0; i < 2; i++) st[j][i] = (floatx4){0.f, 0.f, 0.f, 0.f};
#pragma unroll
    for (int kd = 0; kd < 4; kd++) {
      half8 kb[4];
#pragma unroll
      for (int j = 0; j < 4; j++)
        kb[j] = *(const half8*)&Ks[cur][j * 16 + l15][kd * 32 + lq * 8];
#pragma unroll
      for (int j = 0; j < 4; j++)
#pragma unroll
        for (int i = 0; i < 2; i++)
          st[j][i] = __builtin_amdgcn_mfma_f32_16x16x32_f16(kb[j], qf[i][kd], st[j][i], 0, 0, 0);
    }

    floatx4 amf[4];
#pragma unroll
    for (int j = 0; j < 4; j++) {
      amf[j][0] = mk4[j].x ? 0.f : -3.0e38f;
      amf[j][1] = mk4[j].y ? 0.f : -3.0e38f;
      amf[j][2] = mk4[j].z ? 0.f : -3.0e38f;
      amf[j][3] = mk4[j].w ? 0.f : -3.0e38f;
    }

    // ---- online softmax (per q-row m: 16 in-thread + 2 butterflies)
    half4 ph[2][4];
#pragma unroll
    for (int i = 0; i < 2; i++) {
      float mx = -3.0e38f;
#pragma unroll
      for (int j = 0; j < 4; j++)
#pragma unroll
        for (int r = 0; r < 4; r++) {
          float v = st[j][i][r] * sl2e + amf[j][r];
          st[j][i][r] = v;
          mx = fmaxf(mx, v);
        }
      mx = fmaxf(mx, __shfl_xor(mx, 16));
      mx = fmaxf(mx, __shfl_xor(mx, 32));
      float mnew  = fmaxf(m_i[i], mx);
      float alpha = __builtin_amdgcn_exp2f(m_i[i] - mnew);
      m_i[i] = mnew;
      float rs = 0.f;
#pragma unroll
      for (int j = 0; j < 4; j++)
#pragma unroll
        for (int r = 0; r < 4; r++) {
          float pv = __builtin_amdgcn_exp2f(st[j][i][r] - mnew);
          ph[i][j][r] = (_Float16)pv;
          rs += pv;
        }
      rs += __shfl_xor(rs, 16);
      rs += __shfl_xor(rs, 32);
      l_i[i] = l_i[i] * alpha + rs;
#pragma unroll
      for (int r = 0; r < 4; r++) {
        float a_r = __shfl(alpha, lq * 4 + r);
#pragma unroll
        for (int jd = 0; jd < 8; jd++) oacc[i][jd][r] *= a_r;
      }
    }

    // ---- O += P V via 16x16x16 (A = ph in-register, B = Vt half4)
#pragma unroll
    for (int j = 0; j < 4; j++) {
#pragma unroll
      for (int jd = 0; jd < 8; jd++) {
        half4 vb = *(const half4*)&Vt[cur][jd * 16 + l15][j * 16 + lq * 4];
#pragma unroll
        for (int i = 0; i < 2; i++)
          oacc[i][jd] = __builtin_amdgcn_mfma_f32_16x16x16f16(ph[i][j], vb, oacc[i][jd], 0, 0, 0);
      }
    }

    // write prefetched tile to the alternate buffer (safe: all waves finished
    // reading it at the previous barrier), then one barrier
    if (has_next) {
      const int nxt = 1 - cur;
#pragma unroll
      for (int it = 0; it < 4; it++) {
        *(half8*)&Ks[nxt][krow[it]][kcol[it]] = kreg[it];
        *(half8*)&Vt[nxt][vrow[it]][vcol[it]] = vreg[it];
      }
    }
    __syncthreads();
  }

  // ---- epilogue
#pragma unroll
  for (int i = 0; i < 2; i++) {
    float linv = 1.0f / l_i[i];
#pragma unroll
    for (int r = 0; r < 4; r++) {
      float lr = __shfl(linv, lq * 4 + r);
      size_t row = (size_t)(b * S_ + q0 + wave * 32 + i * 16 + lq * 4 + r);
#pragma unroll
      for (int jd = 0; jd < 8; jd++)
        Obuf[row * HID_ + h * HD_ + jd * 16 + l15] = (_Float16)(oacc[i][jd][r] * lr);
    }
  }
}

// ---------------------------------------------------------------------------
extern "C" void kernel_launch(void* const* d_in, const int* in_sizes, int n_in,
                              void* d_out, int out_size, void* d_ws, size_t ws_size,
                              hipStream_t stream) {
  const float* hidden = (const float*)d_in[0];
  const int*   mask   = (const int*)d_in[1];
  const float* Wq = (const float*)d_in[2];
  const float* bq = (const float*)d_in[3];
  const float* Wk = (const float*)d_in[4];
  const float* bk = (const float*)d_in[5];
  const float* Wv = (const float*)d_in[6];
  const float* bv = (const float*)d_in[7];
  const float* Wo = (const float*)d_in[8];
  const float* bo = (const float*)d_in[9];
  float* out = (float*)d_out;

  char* p = (char*)d_ws;
  auto alloc = [&](size_t bytes) {
    char* r = p;
    p += (bytes + 255) & ~(size_t)255;
    return r;
  };
  _Float16* hidh = (_Float16*)alloc((size_t)M_ * HID_ * 2);
  _Float16* Wqh  = (_Float16*)alloc((size_t)HID_ * HID_ * 2);
  _Float16* Wkh  = (_Float16*)alloc((size_t)HD_ * HID_ * 2);
  _Float16* Wvh  = (_Float16*)alloc((size_t)HD_ * HID_ * 2);
  _Float16* Woh  = (_Float16*)alloc((size_t)HID_ * HID_ * 2);
  _Float16* Qh   = (_Float16*)alloc((size_t)M_ * HID_ * 2);
  _Float16* Kh   = (_Float16*)alloc((size_t)M_ * HD_ * 2);
  _Float16* VhT  = (_Float16*)alloc((size_t)M_ * HD_ * 2);
  _Float16* attnh = (_Float16*)alloc((size_t)M_ * HID_ * 2);

  // one fused fp32 -> fp16 cast (8448 blocks)
  cvt_all<<<8448, 256, 0, stream>>>(hidden, Wq, Wk, Wv, Wo,
                                    hidh, Wqh, Wkh, Wvh, Woh);

  // fused Q/K/V projection (V written transposed): 18 x 32 tiles
  dim3 gqkv(18, M_ / 128);
  gemm_qkv<<<gqkv, 256, 0, stream>>>(hidh, Wqh, bq, Qh, Wkh, bk, Kh, Wvh, bv, VhT);

  // attention (S^T flash, dbuf K/V)
  dim3 ga(S_ / 128, B_ * NH_);  // (16, 32)
  attn_mfma<<<ga, 256, 0, stream>>>(Qh, Kh, VhT, mask, attnh);

  // output projection -> d_out (fp32)
  dim3 go(HID_ / 128, M_ / 128);
  gemm_out<<<go, 256, 0, stream>>>(attnh, Woh, bo, out);
}